// Round 14
// baseline (1145.806 us; speedup 1.0000x reference)
//
#include <hip/hip_runtime.h>
#include <hip/hip_bf16.h>
#include <hip/hip_fp16.h>

typedef unsigned int uint32;
typedef _Float16 hf2 __attribute__((ext_vector_type(2)));
typedef signed char i8x4 __attribute__((ext_vector_type(4)));

#define NT 1024

// ---------- helpers ----------
__device__ __forceinline__ float bfu(unsigned short v) { return __uint_as_float(((uint32)v) << 16); }
__device__ __forceinline__ unsigned short f2bf(float f) {
    uint32 u = __float_as_uint(f);
    u = (u + 0x7fffu + ((u >> 16) & 1u)) >> 16;
    return (unsigned short)u;
}
__device__ __forceinline__ uint32 pack_f16(float a, float b) {
    __half ha = __float2half_rn(a), hb = __float2half_rn(b);
    return (uint32)__half_as_ushort(ha) | ((uint32)__half_as_ushort(hb) << 16);
}
__device__ __forceinline__ float fexp2(float x) {
#if __has_builtin(__builtin_amdgcn_exp2f)
    return __builtin_amdgcn_exp2f(x);
#else
    return exp2f(x);
#endif
}
__device__ __forceinline__ float frcp(float x) {
#if __has_builtin(__builtin_amdgcn_rcpf)
    return __builtin_amdgcn_rcpf(x);
#else
    return __fdividef(1.f, x);
#endif
}
// tanh = 1 - 2/(1+e^{2x}); saturates correctly, no clamp needed.
__device__ __forceinline__ float fast_tanh(float x) {
    float e = fexp2(x * 2.8853900817779268f);  // 2*log2(e)
    return fmaf(-2.f, frcp(1.f + e), 1.f);
}
__device__ __forceinline__ float fast_sigmoid(float x) {
    return frcp(1.f + fexp2(-1.4426950408889634f * x));
}
// broadcast lane k's value (k wave-uniform) without DS traffic
__device__ __forceinline__ float rdlane(float v, int k) {
#if __has_builtin(__builtin_amdgcn_readlane)
    return __builtin_bit_cast(float, __builtin_amdgcn_readlane(__builtin_bit_cast(int, v), k));
#else
    return __shfl(v, k);
#endif
}
// 2-way f16 dot with f32 accumulate (v_dot2_f32_f16), guarded fallback
__device__ __forceinline__ float fdot2(uint32 w, uint32 v, float acc) {
#if __has_builtin(__builtin_amdgcn_fdot2)
    return __builtin_amdgcn_fdot2(__builtin_bit_cast(hf2, w), __builtin_bit_cast(hf2, v), acc, false);
#else
    __half2 wh = __builtin_bit_cast(__half2, w), vh = __builtin_bit_cast(__half2, v);
    float2 wf = __half22float2(wh), vf = __half22float2(vh);
    return fmaf(wf.y, vf.y, fmaf(wf.x, vf.x, acc));
#endif
}
// 4-way i8 dot with i32 accumulate (v_dot4_i32_i8), guarded exact fallback
__device__ __forceinline__ int dot4i8(uint32 a, uint32 b, int acc) {
#if __has_builtin(__builtin_amdgcn_sdot4)
    return __builtin_amdgcn_sdot4(__builtin_bit_cast(int, a), __builtin_bit_cast(int, b), acc, false);
#else
    i8x4 x = __builtin_bit_cast(i8x4, a), y = __builtin_bit_cast(i8x4, b);
    return acc + (int)x.x * y.x + (int)x.y * y.y + (int)x.z * y.z + (int)x.w * y.w;
#endif
}

// LDS flag ops (workgroup scope)
// sleep variant: for slack-rich waves
template <int S>
__device__ __forceinline__ void spin_ge(uint32* p, uint32 tgt) {
    if (__hip_atomic_load(p, __ATOMIC_ACQUIRE, __HIP_MEMORY_SCOPE_WORKGROUP) >= tgt) return;
    int guard = 0;
    do {
        __builtin_amdgcn_s_sleep(S);
        if (++guard > (1 << 22)) break;  // safety valve: wrong answer beats a hang
    } while (__hip_atomic_load(p, __ATOMIC_ACQUIRE, __HIP_MEMORY_SCOPE_WORKGROUP) < tgt);
}
// busy variant: chain-critical wakes — no sleep quantization
__device__ __forceinline__ void spin_busy(uint32* p, uint32 tgt) {
    int guard = 0;
    while (__hip_atomic_load(p, __ATOMIC_ACQUIRE, __HIP_MEMORY_SCOPE_WORKGROUP) < tgt) {
        if (++guard > (1 << 24)) break;  // safety valve
    }
}
__device__ __forceinline__ void st_flag(uint32* p, uint32 v) {
    __hip_atomic_store(p, v, __ATOMIC_RELEASE, __HIP_MEMORY_SCOPE_WORKGROUP);
}
__device__ __forceinline__ void add_flag(uint32* p, uint32 v) {
    __hip_atomic_fetch_add(p, v, __ATOMIC_RELEASE, __HIP_MEMORY_SCOPE_WORKGROUP);
}

// ---------- prep 1: f16 We2 + f16 xw + f16 h-tail + int8 W_hh head ----------
// (identical to r13)
__global__ void prep_weights(const float* __restrict__ We, const float* __restrict__ W_ih,
                             const float* __restrict__ W_hh, uint32* __restrict__ We2,
                             uint32* __restrict__ Wc2, uint32* __restrict__ Wq) {
    int idx = blockIdx.x * 256 + threadIdx.x;
    if (idx < 32768) {
        int p = idx & 3, s = (idx >> 2) & 127, jq = idx >> 9;
        int j = 8 * jq + 2 * p;
        We2[idx] = pack_f16(We[s * 512 + j], We[s * 512 + j + 1]);
    } else if (idx < 98304) {
        int i2 = idx - 32768;  // [0, 65536): xw f16 region1
        int p = i2 & 3, q = (i2 >> 2) & 255, np = i2 >> 10;
        int g = 4 * q + p;
        Wc2[i2] = pack_f16(W_ih[g * 128 + 2 * np], W_ih[g * 128 + 2 * np + 1]);
    } else if (idx < 131072) {
        int i3 = idx - 98304;  // [0, 32768): h-tail f16 region2 (cols 192..255)
        int p = i3 & 3, q = (i3 >> 2) & 255, npr96 = i3 >> 10;
        int g = 4 * q + p;
        int col = 2 * (96 + npr96);
        Wc2[65536 + i3] = pack_f16(W_hh[g * 256 + col], W_hh[g * 256 + col + 1]);
    } else if (idx < 196608) {
        int i4 = idx - 131072;  // [0, 65536): int8 W_hh head
        int m = i4 >> 10, g = i4 & 1023;
        uint32 wv = 0;
#pragma unroll
        for (int k = 0; k < 4; ++k) {
            float w = W_hh[g * 256 + 4 * m + k];
            int wi = (int)rintf(w * 2032.0f);  // 127/0.0625
            wi = wi > 127 ? 127 : (wi < -127 ? -127 : wi);
            wv |= ((uint32)(wi & 0xFF)) << (8 * k);
        }
        Wq[i4] = wv;
    }
}

// ---------- prep 2: Ux[b,s,n] = sum_t x[b,t,n] * Ue[s,t]  (bf16 out) ----------
__global__ void ux_kernel(const float* __restrict__ x, const float* __restrict__ Ue,
                          unsigned short* __restrict__ Uxg) {
    int b = blockIdx.x >> 1, h = blockIdx.x & 1;
    int n = threadIdx.x & 127, sg = threadIdx.x >> 7;
    int s0 = h * 64 + sg * 16;
    float acc[16];
#pragma unroll
    for (int k = 0; k < 16; ++k) acc[k] = 0.f;
    for (int t0 = 0; t0 < 128; t0 += 16) {
        float xv[16];
#pragma unroll
        for (int tt = 0; tt < 16; ++tt) xv[tt] = x[(b * 128 + t0 + tt) * 128 + n];
#pragma unroll
        for (int k = 0; k < 16; ++k) {
            const float4* uep = (const float4*)(Ue + (s0 + k) * 128 + t0);
            float4 u0 = uep[0], u1 = uep[1], u2 = uep[2], u3 = uep[3];
            acc[k] += xv[0] * u0.x + xv[1] * u0.y + xv[2] * u0.z + xv[3] * u0.w
                    + xv[4] * u1.x + xv[5] * u1.y + xv[6] * u1.z + xv[7] * u1.w
                    + xv[8] * u2.x + xv[9] * u2.y + xv[10] * u2.z + xv[11] * u2.w
                    + xv[12] * u3.x + xv[13] * u3.y + xv[14] * u3.z + xv[15] * u3.w;
        }
    }
#pragma unroll
    for (int k = 0; k < 16; ++k)
        Uxg[b * 16384 + (s0 + k) * 128 + n] = f2bf(acc[k]);
}

// ---------- main: 128 blocks, wave-specialized, barrier-free step loop ----------
// int8 h-stream, MINIMAL-WORK quantize placement (closes the r11/r12/r13 arc):
//   B thread j<192 quantizes ITS OWN h (7 VALU) and writes 2 ds_write_b8 into
//   vhq_a/vhq_b byte j — no shuffles, no redundancy, no extra live state.
//   h-waves g0-2 read the packed words directly (uint4) and run the merged-acc
//   dot4 loop (zero quantize VALU, ~r9's op count). Release: each B wave's cnt5
//   DS-atomic add orders its prior byte stores; consumers gate on cnt5>=4t.
//   g3: f16 tail cols 192..255; g4/5: ph1 (24 LDS + 8 L2 jq) then xw stream.
// Flags unchanged: cnt1=4, cnt2=4, cnt4=13 (12 A + inv), cnt5=4, xw_flag.
__global__ __launch_bounds__(NT, 4)
void encoder_kernel(const float* __restrict__ x, const float* __restrict__ v_e,
                    const float* __restrict__ b_ih, const float* __restrict__ b_hh,
                    const unsigned short* __restrict__ Uxg, const uint4* __restrict__ We2q,
                    const uint4* __restrict__ Wc2q, const uint32* __restrict__ Wq,
                    float* __restrict__ out) {
    __shared__ __align__(16) unsigned short Ux_s[16384];  // 32 KB [s][n] bf16
    __shared__ __align__(16) uint4 We2L[6144];            // 96 KB We2 jq[0,48)
    __shared__ __align__(16) float part4[6144];           // 24 KB [grp][1024 gates]
    __shared__ float part1[256];                          // [jg][s]
    __shared__ float part2[256];                          // [sg][n]
    __shared__ __align__(16) uint32 vh_s[64];    // half2 pairs of x*e (xw stream operand)
    __shared__ __align__(16) uint32 vhq_a[48];   // int8 h main, byte j = round(127*h[j])
    __shared__ __align__(16) uint32 vhq_b[48];   // int8 h residual (x254)
    __shared__ __align__(16) uint32 hsh_s[256];  // half2 pairs hs=[h(0..128)|c(128..256)]
    __shared__ float c_s[256];                   // f32 c state
    __shared__ float inv_s;                      // 1/sum(e) for current step
    __shared__ uint32 xw_flag, cnt1, cnt2, cnt4, cnt5;

    const int tid = threadIdx.x;
    const int b = blockIdx.x;

    {   // load this batch's Ux tile (coalesced)
        const uint4* src = (const uint4*)(Uxg + b * 16384);
        uint4* dst = (uint4*)Ux_s;
        for (int i = tid; i < 2048; i += NT) dst[i] = src[i];
    }
    // stage We2 jq[0,48) in LDS (96 KB; chain-head reads become port-free)
    for (int i = tid; i < 6144; i += NT) We2L[i] = We2q[i];
    if (tid < 64) vh_s[tid] = 0u;
    if (tid < 48) { vhq_a[tid] = 0u; vhq_b[tid] = 0u; }
    if (tid < 256) { hsh_s[tid] = 0u; c_s[tid] = 0.f; }
    if (tid == 0) { xw_flag = 0; cnt1 = 0; cnt2 = 0; cnt4 = 0; cnt5 = 0; inv_s = 0.f; }
    // B-thread bias registers
    float bi0 = 0.f, bf0 = 0.f, bg0 = 0.f, bo0 = 0.f;
    if (tid >= 768) {
        int j = tid - 768;
        bi0 = b_ih[j] + b_hh[j];
        bf0 = b_ih[256 + j] + b_hh[256 + j];
        bg0 = b_ih[512 + j] + b_hh[512 + j];
        bo0 = b_ih[768 + j] + b_hh[768 + j];
    }
    __syncthreads();  // the only barrier; all threads reach it

// 4-np f16 stream block (xw): 1 ds_read_b128 + 8 b128 weight loads + 32 fdot2
#define NP_BLOCK(npb)                                                \
    {                                                                \
        uint4 vp4 = *(const uint4*)&vh_s[(npb)];                     \
        _Pragma("unroll")                                            \
        for (int u = 0; u < 4; ++u) {                                \
            uint32 vp = (&vp4.x)[u];                                 \
            const uint4* wp = wc + ((npb) + u) * 256;                \
            uint4 w0 = wp[0], w1 = wp[1];                            \
            a0 = fdot2(w0.x, vp, a0); a1 = fdot2(w0.y, vp, a1);      \
            a2 = fdot2(w0.z, vp, a2); a3 = fdot2(w0.w, vp, a3);      \
            a4 = fdot2(w1.x, vp, a4); a5 = fdot2(w1.y, vp, a5);      \
            a6 = fdot2(w1.z, vp, a6); a7 = fdot2(w1.w, vp, a7);      \
        }                                                            \
    }

    if (tid < 512) {
        const int ol = tid & 127, g = tid >> 7;
        if (g < 3) {
            // ===== int8 two-level h GEMV (merged acc, packed-word reads) =====
            const uint32* wqb = Wq + 8 * ol;       // + m*1024
            const int m0 = 16 * g;
            const float S2 = 6.25e-2f / 16129.f / 254.f;  // C=254A+B -> S2*C
            for (int t = 0; t < 128; ++t) {
                spin_ge<4>(&cnt5, (uint32)(4 * t));
                int c0 = 0, c1 = 0, c2 = 0, c3 = 0;
                int c4 = 0, c5 = 0, c6 = 0, c7 = 0;
#pragma unroll
                for (int i = 0; i < 4; ++i) {
                    uint4 ha4 = *(const uint4*)&vhq_a[m0 + 4 * i];
                    uint4 hb4 = *(const uint4*)&vhq_b[m0 + 4 * i];
#pragma unroll
                    for (int u = 0; u < 4; ++u) {
                        uint32 ha = (&ha4.x)[u], hb = (&hb4.x)[u];
                        const uint4* wp = (const uint4*)(wqb + (m0 + 4 * i + u) * 1024);
                        uint4 w0 = wp[0], w1 = wp[1];
                        int t0;
                        t0 = dot4i8(w0.x, ha, 0); c0 = dot4i8(w0.x, hb, c0) + t0 * 254;
                        t0 = dot4i8(w0.y, ha, 0); c1 = dot4i8(w0.y, hb, c1) + t0 * 254;
                        t0 = dot4i8(w0.z, ha, 0); c2 = dot4i8(w0.z, hb, c2) + t0 * 254;
                        t0 = dot4i8(w0.w, ha, 0); c3 = dot4i8(w0.w, hb, c3) + t0 * 254;
                        t0 = dot4i8(w1.x, ha, 0); c4 = dot4i8(w1.x, hb, c4) + t0 * 254;
                        t0 = dot4i8(w1.y, ha, 0); c5 = dot4i8(w1.y, hb, c5) + t0 * 254;
                        t0 = dot4i8(w1.z, ha, 0); c6 = dot4i8(w1.z, hb, c6) + t0 * 254;
                        t0 = dot4i8(w1.w, ha, 0); c7 = dot4i8(w1.w, hb, c7) + t0 * 254;
                    }
                }
                float4* p4 = (float4*)&part4[g * 1024 + 8 * ol];
                p4[0] = make_float4(S2 * (float)c0, S2 * (float)c1,
                                    S2 * (float)c2, S2 * (float)c3);
                p4[1] = make_float4(S2 * (float)c4, S2 * (float)c5,
                                    S2 * (float)c6, S2 * (float)c7);
                if ((tid & 63) == 0) add_flag(&cnt4, 1);
            }
        } else {
            // ===== f16 h-tail GEMV: cols 192..255 from Wc2 region2 =====
            const uint4* wch = Wc2q + 16384 + 2 * ol;  // region2 base (uint4)
            for (int t = 0; t < 128; ++t) {
                spin_ge<4>(&cnt5, (uint32)(4 * t));
                float a0 = 0.f, a1 = 0.f, a2 = 0.f, a3 = 0.f;
                float a4 = 0.f, a5 = 0.f, a6 = 0.f, a7 = 0.f;
#pragma unroll 2
                for (int blk = 0; blk < 8; ++blk) {
                    const int nl = 4 * blk;
                    uint4 vp4 = *(const uint4*)&hsh_s[96 + nl];
#pragma unroll
                    for (int u = 0; u < 4; ++u) {
                        uint32 vp = (&vp4.x)[u];
                        const uint4* wp = wch + (nl + u) * 256;
                        uint4 w0 = wp[0], w1 = wp[1];
                        a0 = fdot2(w0.x, vp, a0); a1 = fdot2(w0.y, vp, a1);
                        a2 = fdot2(w0.z, vp, a2); a3 = fdot2(w0.w, vp, a3);
                        a4 = fdot2(w1.x, vp, a4); a5 = fdot2(w1.y, vp, a5);
                        a6 = fdot2(w1.z, vp, a6); a7 = fdot2(w1.w, vp, a7);
                    }
                }
                float4* p4 = (float4*)&part4[3 * 1024 + 8 * ol];
                p4[0] = make_float4(a0, a1, a2, a3);
                p4[1] = make_float4(a4, a5, a6, a7);
                if ((tid & 63) == 0) add_flag(&cnt4, 1);
            }
        }
    } else if (tid < 768) {
        // ============ ph1 waves (chain head) + xw f16 tail stream ============
        __builtin_amdgcn_s_setprio(1);
        const int ol = tid & 127, jg = (tid >> 7) - 4;
        const uint4* wc = Wc2q + 2 * ol;
        const int s = ol;
        const int lq0 = jg * 24;      // LDS jq base: 0 or 24
        const int gq0 = 48 + jg * 8;  // L2 jq base: 48 or 56
        for (int t = 0; t < 128; ++t) {
            float a0 = 0.f, a1 = 0.f, a2 = 0.f, a3 = 0.f;
            float a4 = 0.f, a5 = 0.f, a6 = 0.f, a7 = 0.f;
            spin_busy(&cnt5, (uint32)(4 * t));
            float acc = 0.f;
#pragma unroll
            for (int jq = gq0; jq < gq0 + 8; ++jq) {
                uint4 w = We2q[jq * 128 + s];
                uint4 hh = *(const uint4*)&hsh_s[4 * jq];
                acc = fdot2(w.x, hh.x, acc);
                acc = fdot2(w.y, hh.y, acc);
                acc = fdot2(w.z, hh.z, acc);
                acc = fdot2(w.w, hh.w, acc);
            }
#pragma unroll 4
            for (int jq = lq0; jq < lq0 + 24; ++jq) {
                uint4 w = We2L[jq * 128 + s];
                uint4 hh = *(const uint4*)&hsh_s[4 * jq];
                acc = fdot2(w.x, hh.x, acc);
                acc = fdot2(w.y, hh.y, acc);
                acc = fdot2(w.z, hh.z, acc);
                acc = fdot2(w.w, hh.w, acc);
            }
            part1[jg * 128 + s] = acc;
            if ((tid & 63) == 0) add_flag(&cnt1, 1);
            // xw-part: np in [32jg, 32jg+32) -- chain tail, fast wake
            spin_busy(&xw_flag, (uint32)(t + 1));
            const int np0 = jg * 32;
#pragma unroll 2
            for (int i = 0; i < 8; ++i) NP_BLOCK(np0 + 4 * i);
            float4* p4 = (float4*)&part4[(4 + jg) * 1024 + 8 * ol];
            p4[0] = make_float4(a0, a1, a2, a3);
            p4[1] = make_float4(a4, a5, a6, a7);
            if ((tid & 63) == 0) add_flag(&cnt4, 1);
        }
    } else {
        // ================= B-group =================
        __builtin_amdgcn_s_setprio(2);  // B is on the chain almost always
        const int bt = tid - 768, l = tid & 63;
        const int n = bt & 127, sg = bt >> 7;
        const float ve_lane = v_e[sg * 64 + l];  // lane l holds ve[sg*64+l]
        const unsigned short* uxrow = Ux_s + sg * 64 * 128 + n;
        signed char* qa8 = (signed char*)vhq_a;
        signed char* qb8 = (signed char*)vhq_b;
        for (int t = 0; t < 128; ++t) {
            float2 xt2;
            if (bt < 64) xt2 = *(const float2*)(x + (b * 128 + t) * 128 + 2 * l);
            spin_busy(&cnt1, (uint32)(4 * (t + 1)));
            // per-wave redundant web: lane l holds web[l], web[64+l]
            float web_lo = part1[l] + part1[128 + l];
            float web_hi = part1[64 + l] + part1[192 + l];
            float wsel = sg ? web_hi : web_lo;
            // ph2: scores partial over s-chunk sg (readlane broadcast, 2 acc chains)
            float acc0 = 0.f, acc1 = 0.f;
#pragma unroll
            for (int k = 0; k < 64; k += 2) {
                float wv0 = rdlane(wsel, k), ve0 = rdlane(ve_lane, k);
                float wv1 = rdlane(wsel, k + 1), ve1 = rdlane(ve_lane, k + 1);
                acc0 = fmaf(ve0, fast_tanh(wv0 + bfu(uxrow[k * 128])), acc0);
                acc1 = fmaf(ve1, fast_tanh(wv1 + bfu(uxrow[(k + 1) * 128])), acc1);
            }
            part2[sg * 128 + n] = acc0 + acc1;
            if (l == 0) add_flag(&cnt2, 1);
            if (bt < 64) {
                // ph3: exp + x*e pack; xw released BEFORE the reduce (defer-norm)
                spin_busy(&cnt2, (uint32)(4 * (t + 1)));
                __builtin_amdgcn_s_setprio(3);
                float v0 = part2[2 * l] + part2[128 + 2 * l];
                float v1 = part2[2 * l + 1] + part2[129 + 2 * l];
                // |score| <= sum|ve| ~ 6 -> e <= ~300, x*e fits f16
                float e0 = fexp2(v0 * 1.4426950408889634f);
                float e1 = fexp2(v1 * 1.4426950408889634f);
                vh_s[l] = pack_f16(xt2.x * e0, xt2.y * e1);  // UNNORMALIZED
                if (bt == 0) st_flag(&xw_flag, (uint32)(t + 1));
                __builtin_amdgcn_s_setprio(2);
                // off-chain: sum-reduce + inv; consumers gated via cnt4 (13th add)
                float ssum = e0 + e1;
#pragma unroll
                for (int off = 32; off > 0; off >>= 1) ssum += __shfl_xor(ssum, off);
                if (bt == 0) { inv_s = frcp(ssum); add_flag(&cnt4, 1); }
            }
            // ph5: gate reduce + LSTM pointwise (all 4 B-waves; thread = h-unit j)
            spin_busy(&cnt4, (uint32)(13 * (t + 1)));
            const float inv = inv_s;
            const int j = bt;
            // h partials (slots 0-3); xw partials (slots 4-5) scaled by inv
            float gi = bi0 + part4[j] + part4[1024 + j] + part4[2048 + j] + part4[3072 + j]
                     + (part4[4096 + j] + part4[5120 + j]) * inv;
            float gf = bf0 + part4[256 + j] + part4[1280 + j] + part4[2304 + j] + part4[3328 + j]
                     + (part4[4352 + j] + part4[5376 + j]) * inv;
            float gg = bg0 + part4[512 + j] + part4[1536 + j] + part4[2560 + j] + part4[3584 + j]
                     + (part4[4608 + j] + part4[5632 + j]) * inv;
            float go = bo0 + part4[768 + j] + part4[1792 + j] + part4[2816 + j] + part4[3840 + j]
                     + (part4[4864 + j] + part4[5888 + j]) * inv;
            float c = c_s[j];
            float c2 = fast_sigmoid(gf) * c + fast_sigmoid(gi) * fast_tanh(gg);
            float h2v = fast_sigmoid(go) * fast_tanh(c2);
            c_s[j] = c2;
            // two-level int8 publish: own byte only, no shuffles (waves 12-14)
            if (bt < 192) {
                float tq = h2v * 127.f;
                float af = rintf(tq);
                qa8[j] = (signed char)(int)af;
                qb8[j] = (signed char)(int)rintf((tq - af) * 254.f);
            }
            float hn = __shfl_xor(h2v, 1);
            float cn = __shfl_xor(c2, 1);
            if (!(j & 1)) {
                hsh_s[j >> 1] = pack_f16(h2v, hn);         // hs h-pairs (ph1 + f16 tail)
                hsh_s[128 + (j >> 1)] = pack_f16(c2, cn);  // hs c-pairs
            }
            if (l == 0) add_flag(&cnt5, 1);  // DS release-add orders prior byte stores
            // global store AFTER the release: keep its vmcnt off the handoff path
            out[(t * 128 + b) * 256 + j] = h2v;
        }
    }
#undef NP_BLOCK
}

extern "C" void kernel_launch(void* const* d_in, const int* in_sizes, int n_in,
                              void* d_out, int out_size, void* d_ws, size_t ws_size,
                              hipStream_t stream) {
    const float* x    = (const float*)d_in[0];
    const float* We   = (const float*)d_in[1];
    const float* Ue   = (const float*)d_in[2];
    const float* v_e  = (const float*)d_in[3];
    const float* W_ih = (const float*)d_in[4];
    const float* W_hh = (const float*)d_in[5];
    const float* b_ih = (const float*)d_in[6];
    const float* b_hh = (const float*)d_in[7];
    float* out = (float*)d_out;

    char* w = (char*)d_ws;
    unsigned short* Uxg = (unsigned short*)w;      // 4 MB
    uint32* We2 = (uint32*)(w + 4194304);          // 128 KB
    uint32* Wc2 = (uint32*)(w + 4325376);          // 384 KB (xw f16 | h-tail f16)
    uint32* Wq  = (uint32*)(w + 4718592);          // 256 KB int8 W_hh head

    prep_weights<<<768, 256, 0, stream>>>(We, W_ih, W_hh, We2, Wc2, Wq);
    ux_kernel<<<256, 512, 0, stream>>>(x, Ue, Uxg);
    encoder_kernel<<<128, NT, 0, stream>>>(x, v_e, b_ih, b_hh, Uxg,
                                           (const uint4*)We2, (const uint4*)Wc2,
                                           Wq, out);
}

// Round 15
// 1053.976 us; speedup vs baseline: 1.0871x; 1.0871x over previous
//
#include <hip/hip_runtime.h>
#include <hip/hip_bf16.h>
#include <hip/hip_fp16.h>

typedef unsigned int uint32;
typedef _Float16 hf2 __attribute__((ext_vector_type(2)));

#define NT 1024

// ---------- helpers ----------
__device__ __forceinline__ float bfu(unsigned short v) { return __uint_as_float(((uint32)v) << 16); }
__device__ __forceinline__ unsigned short f2bf(float f) {
    uint32 u = __float_as_uint(f);
    u = (u + 0x7fffu + ((u >> 16) & 1u)) >> 16;
    return (unsigned short)u;
}
__device__ __forceinline__ uint32 pack_f16(float a, float b) {
    __half ha = __float2half_rn(a), hb = __float2half_rn(b);
    return (uint32)__half_as_ushort(ha) | ((uint32)__half_as_ushort(hb) << 16);
}
__device__ __forceinline__ float fexp2(float x) {
#if __has_builtin(__builtin_amdgcn_exp2f)
    return __builtin_amdgcn_exp2f(x);
#else
    return exp2f(x);
#endif
}
__device__ __forceinline__ float frcp(float x) {
#if __has_builtin(__builtin_amdgcn_rcpf)
    return __builtin_amdgcn_rcpf(x);
#else
    return __fdividef(1.f, x);
#endif
}
// tanh = 1 - 2/(1+e^{2x}); saturates correctly, no clamp needed.
__device__ __forceinline__ float fast_tanh(float x) {
    float e = fexp2(x * 2.8853900817779268f);  // 2*log2(e)
    return fmaf(-2.f, frcp(1.f + e), 1.f);
}
__device__ __forceinline__ float fast_sigmoid(float x) {
    return frcp(1.f + fexp2(-1.4426950408889634f * x));
}
// broadcast lane k's value (k wave-uniform) without DS traffic
__device__ __forceinline__ float rdlane(float v, int k) {
#if __has_builtin(__builtin_amdgcn_readlane)
    return __builtin_bit_cast(float, __builtin_amdgcn_readlane(__builtin_bit_cast(int, v), k));
#else
    return __shfl(v, k);
#endif
}
// 2-way f16 dot with f32 accumulate (v_dot2_f32_f16), guarded fallback
__device__ __forceinline__ float fdot2(uint32 w, uint32 v, float acc) {
#if __has_builtin(__builtin_amdgcn_fdot2)
    return __builtin_amdgcn_fdot2(__builtin_bit_cast(hf2, w), __builtin_bit_cast(hf2, v), acc, false);
#else
    __half2 wh = __builtin_bit_cast(__half2, w), vh = __builtin_bit_cast(__half2, v);
    float2 wf = __half22float2(wh), vf = __half22float2(vh);
    return fmaf(wf.y, vf.y, fmaf(wf.x, vf.x, acc));
#endif
}

// LDS flag ops (workgroup scope)
// sleep variant: for slack-rich waves (poll cost matters less than issue slots)
template <int S>
__device__ __forceinline__ void spin_ge(uint32* p, uint32 tgt) {
    if (__hip_atomic_load(p, __ATOMIC_ACQUIRE, __HIP_MEMORY_SCOPE_WORKGROUP) >= tgt) return;
    int guard = 0;
    do {
        __builtin_amdgcn_s_sleep(S);
        if (++guard > (1 << 22)) break;  // safety valve: wrong answer beats a hang
    } while (__hip_atomic_load(p, __ATOMIC_ACQUIRE, __HIP_MEMORY_SCOPE_WORKGROUP) < tgt);
}
// busy variant: for chain-critical wakes — no sleep quantization (~64-256cy saved)
__device__ __forceinline__ void spin_busy(uint32* p, uint32 tgt) {
    int guard = 0;
    while (__hip_atomic_load(p, __ATOMIC_ACQUIRE, __HIP_MEMORY_SCOPE_WORKGROUP) < tgt) {
        if (++guard > (1 << 24)) break;  // safety valve
    }
}
__device__ __forceinline__ void st_flag(uint32* p, uint32 v) {
    __hip_atomic_store(p, v, __ATOMIC_RELEASE, __HIP_MEMORY_SCOPE_WORKGROUP);
}
__device__ __forceinline__ void add_flag(uint32* p, uint32 v) {
    __hip_atomic_fetch_add(p, v, __ATOMIC_RELEASE, __HIP_MEMORY_SCOPE_WORKGROUP);
}

// ---------- prep 1: f16-convert + re-layout weights (r1 layout, proven) ----------
// We2: uint4[64][128]; [jq][s] = 4 half2 of We rows (hs reduction j in [0,512))
// Wc2: uint4[192][256]; [np][q] = 4 half2: gate g=4q+p gets (W[g][2np], W[g][2np+1])
//      K-dim n in [0,384) = [xw(128)|h(256)]
__global__ void prep_weights(const float* __restrict__ We, const float* __restrict__ W_ih,
                             const float* __restrict__ W_hh, uint32* __restrict__ We2,
                             uint32* __restrict__ Wc2) {
    int idx = blockIdx.x * 256 + threadIdx.x;
    if (idx < 32768) {
        int p = idx & 3, s = (idx >> 2) & 127, jq = idx >> 9;
        int j = 8 * jq + 2 * p;
        We2[idx] = pack_f16(We[s * 512 + j], We[s * 512 + j + 1]);
    } else if (idx < 229376) {
        int i2 = idx - 32768;
        int p = i2 & 3, q = (i2 >> 2) & 255, np = i2 >> 10;
        int g = 4 * q + p;
        int n0 = 2 * np, n1 = 2 * np + 1;
        float w0, w1;
        if (n0 < 128) {
            w0 = W_ih[g * 128 + n0];
            w1 = W_ih[g * 128 + n1];
        } else {
            w0 = W_hh[g * 256 + (n0 - 128)];
            w1 = W_hh[g * 256 + (n1 - 128)];
        }
        Wc2[i2] = pack_f16(w0, w1);
    }
}

// ---------- prep 2: Ux[b,s,n] = sum_t x[b,t,n] * Ue[s,t]  (bf16 out) ----------
__global__ void ux_kernel(const float* __restrict__ x, const float* __restrict__ Ue,
                          unsigned short* __restrict__ Uxg) {
    int b = blockIdx.x >> 1, h = blockIdx.x & 1;
    int n = threadIdx.x & 127, sg = threadIdx.x >> 7;
    int s0 = h * 64 + sg * 16;
    float acc[16];
#pragma unroll
    for (int k = 0; k < 16; ++k) acc[k] = 0.f;
    for (int t0 = 0; t0 < 128; t0 += 16) {
        float xv[16];
#pragma unroll
        for (int tt = 0; tt < 16; ++tt) xv[tt] = x[(b * 128 + t0 + tt) * 128 + n];
#pragma unroll
        for (int k = 0; k < 16; ++k) {
            const float4* uep = (const float4*)(Ue + (s0 + k) * 128 + t0);
            float4 u0 = uep[0], u1 = uep[1], u2 = uep[2], u3 = uep[3];
            acc[k] += xv[0] * u0.x + xv[1] * u0.y + xv[2] * u0.z + xv[3] * u0.w
                    + xv[4] * u1.x + xv[5] * u1.y + xv[6] * u1.z + xv[7] * u1.w
                    + xv[8] * u2.x + xv[9] * u2.y + xv[10] * u2.z + xv[11] * u2.w
                    + xv[12] * u3.x + xv[13] * u3.y + xv[14] * u3.z + xv[15] * u3.w;
        }
    }
#pragma unroll
    for (int k = 0; k < 16; ++k)
        Uxg[b * 16384 + (s0 + k) * 128 + n] = f2bf(acc[k]);
}

// ---------- main: 128 blocks, wave-specialized, barrier-free step loop ----------
// r8 structure (1225us verified: 96KB We2 LDS staging) + 3 chain cuts:
//   (1) defer-norm softmax: xw_flag released before sum-reduce; 1/sum -> inv_s;
//       ph5 scales the xw partials (part4 slots 4/5 are pure xw). cnt4 = 13.
//   (2) ph1 L2 slice balanced: each jg reads 24 LDS-jq + 8 L2-jq (L2 issued first).
//   (3) busy-wait (no s_sleep) on chain-critical spins; g0-3 keep sleep(4).
__global__ __launch_bounds__(NT, 4)
void encoder_kernel(const float* __restrict__ x, const float* __restrict__ v_e,
                    const float* __restrict__ b_ih, const float* __restrict__ b_hh,
                    const unsigned short* __restrict__ Uxg, const uint4* __restrict__ We2q,
                    const uint4* __restrict__ Wc2q, float* __restrict__ out) {
    __shared__ __align__(16) unsigned short Ux_s[16384];  // 32 KB [s][n] bf16
    __shared__ __align__(16) uint4 We2L[6144];            // 96 KB We2 jq[0,48)
    __shared__ __align__(16) float part4[6144];           // 24 KB [grp][1024 gates]
    __shared__ float part1[256];                          // [jg][s]
    __shared__ float part2[256];                          // [sg][n]
    __shared__ __align__(16) uint32 vh_s[192];   // half2 pairs of v=[x*e(0..64)|h(64..192)]
    __shared__ __align__(16) uint32 hsh_s[256];  // half2 pairs of hs=[h(0..128)|c(128..256)]
    __shared__ float c_s[256];                   // f32 c state
    __shared__ float inv_s;                      // 1/sum(e) for current step
    __shared__ uint32 xw_flag, cnt1, cnt2, cnt4, cnt5;

    const int tid = threadIdx.x;
    const int b = blockIdx.x;

    {   // load this batch's Ux tile (coalesced)
        const uint4* src = (const uint4*)(Uxg + b * 16384);
        uint4* dst = (uint4*)Ux_s;
        for (int i = tid; i < 2048; i += NT) dst[i] = src[i];
    }
    // stage We2 jq[0,48) in LDS (96 KB; chain-head reads become port-free)
    for (int i = tid; i < 6144; i += NT) We2L[i] = We2q[i];
    if (tid < 192) vh_s[tid] = 0u;
    if (tid < 256) { hsh_s[tid] = 0u; c_s[tid] = 0.f; }
    if (tid == 0) { xw_flag = 0; cnt1 = 0; cnt2 = 0; cnt4 = 0; cnt5 = 0; inv_s = 0.f; }
    // B-thread bias registers (replaces bias_s LDS)
    float bi0 = 0.f, bf0 = 0.f, bg0 = 0.f, bo0 = 0.f;
    if (tid >= 768) {
        int j = tid - 768;
        bi0 = b_ih[j] + b_hh[j];
        bf0 = b_ih[256 + j] + b_hh[256 + j];
        bg0 = b_ih[512 + j] + b_hh[512 + j];
        bo0 = b_ih[768 + j] + b_hh[768 + j];
    }
    __syncthreads();  // the only barrier; all threads reach it

// 4-np stream block: 1 ds_read_b128 of v-pairs + 8 b128 weight loads + 32 fdot2
#define NP_BLOCK(npb)                                                \
    {                                                                \
        uint4 vp4 = *(const uint4*)&vh_s[(npb)];                     \
        _Pragma("unroll")                                            \
        for (int u = 0; u < 4; ++u) {                                \
            uint32 vp = (&vp4.x)[u];                                 \
            const uint4* wp = wc + ((npb) + u) * 256;                \
            uint4 w0 = wp[0], w1 = wp[1];                            \
            a0 = fdot2(w0.x, vp, a0); a1 = fdot2(w0.y, vp, a1);      \
            a2 = fdot2(w0.z, vp, a2); a3 = fdot2(w0.w, vp, a3);      \
            a4 = fdot2(w1.x, vp, a4); a5 = fdot2(w1.y, vp, a5);      \
            a6 = fdot2(w1.z, vp, a6); a7 = fdot2(w1.w, vp, a7);      \
        }                                                            \
    }

    if (tid < 768) {
        // ================= A-group =================
        const int ol = tid & 127, g = tid >> 7;
        if (g >= 4) __builtin_amdgcn_s_setprio(1);  // ph1/xw are chain phases
        const uint4* wc = Wc2q + 2 * ol;
        for (int t = 0; t < 128; ++t) {
            float a0 = 0.f, a1 = 0.f, a2 = 0.f, a3 = 0.f;
            float a4 = 0.f, a5 = 0.f, a6 = 0.f, a7 = 0.f;
            if (g < 4) {
                // h-part has thousands of cycles of slack: cheap slow polls
                spin_ge<4>(&cnt5, (uint32)(4 * t));
                const int np0 = 64 + g * 32;
#pragma unroll 2
                for (int i = 0; i < 8; ++i) NP_BLOCK(np0 + 4 * i);
            } else {
                spin_busy(&cnt5, (uint32)(4 * t));
                // ph1: web partial; balanced split: 8 L2 jq (issued first) + 24 LDS jq
                const int s = ol, jg = g - 4;
                const int lq0 = jg * 24;      // LDS jq base: 0 or 24
                const int gq0 = 48 + jg * 8;  // L2 jq base: 48 or 56
                float acc = 0.f;
#pragma unroll
                for (int jq = gq0; jq < gq0 + 8; ++jq) {
                    uint4 w = We2q[jq * 128 + s];
                    uint4 hh = *(const uint4*)&hsh_s[4 * jq];
                    acc = fdot2(w.x, hh.x, acc);
                    acc = fdot2(w.y, hh.y, acc);
                    acc = fdot2(w.z, hh.z, acc);
                    acc = fdot2(w.w, hh.w, acc);
                }
#pragma unroll 4
                for (int jq = lq0; jq < lq0 + 24; ++jq) {
                    uint4 w = We2L[jq * 128 + s];
                    uint4 hh = *(const uint4*)&hsh_s[4 * jq];
                    acc = fdot2(w.x, hh.x, acc);
                    acc = fdot2(w.y, hh.y, acc);
                    acc = fdot2(w.z, hh.z, acc);
                    acc = fdot2(w.w, hh.w, acc);
                }
                part1[jg * 128 + s] = acc;
                if ((tid & 63) == 0) add_flag(&cnt1, 1);
                // xw-part: np in [32(g-4), 32(g-4)+32) -- chain tail, fast wake
                spin_busy(&xw_flag, (uint32)(t + 1));
                const int np0 = jg * 32;
#pragma unroll 2
                for (int i = 0; i < 8; ++i) NP_BLOCK(np0 + 4 * i);
            }
            float4* p4 = (float4*)&part4[g * 1024 + 8 * ol];
            p4[0] = make_float4(a0, a1, a2, a3);
            p4[1] = make_float4(a4, a5, a6, a7);
            if ((tid & 63) == 0) add_flag(&cnt4, 1);
        }
    } else {
        // ================= B-group =================
        __builtin_amdgcn_s_setprio(2);  // B is on the chain almost always
        const int bt = tid - 768, l = tid & 63;
        const int n = bt & 127, sg = bt >> 7;
        const float ve_lane = v_e[sg * 64 + l];  // lane l holds ve[sg*64+l]
        const unsigned short* uxrow = Ux_s + sg * 64 * 128 + n;
        for (int t = 0; t < 128; ++t) {
            float2 xt2;
            if (bt < 64) xt2 = *(const float2*)(x + (b * 128 + t) * 128 + 2 * l);
            spin_busy(&cnt1, (uint32)(4 * (t + 1)));
            // per-wave redundant web: lane l holds web[l], web[64+l]
            float web_lo = part1[l] + part1[128 + l];
            float web_hi = part1[64 + l] + part1[192 + l];
            float wsel = sg ? web_hi : web_lo;
            // ph2: scores partial over s-chunk sg (readlane broadcast, 2 acc chains)
            float acc0 = 0.f, acc1 = 0.f;
#pragma unroll
            for (int k = 0; k < 64; k += 2) {
                float wv0 = rdlane(wsel, k), ve0 = rdlane(ve_lane, k);
                float wv1 = rdlane(wsel, k + 1), ve1 = rdlane(ve_lane, k + 1);
                acc0 = fmaf(ve0, fast_tanh(wv0 + bfu(uxrow[k * 128])), acc0);
                acc1 = fmaf(ve1, fast_tanh(wv1 + bfu(uxrow[(k + 1) * 128])), acc1);
            }
            part2[sg * 128 + n] = acc0 + acc1;
            if (l == 0) add_flag(&cnt2, 1);
            if (bt < 64) {
                // ph3: biased-free exp + x*e pack; xw released BEFORE the reduce
                spin_busy(&cnt2, (uint32)(4 * (t + 1)));
                __builtin_amdgcn_s_setprio(3);
                float v0 = part2[2 * l] + part2[128 + 2 * l];
                float v1 = part2[2 * l + 1] + part2[129 + 2 * l];
                // |score| <= sum|ve| ~ 6 -> e <= ~300, x*e <= ~1500 fits f16
                float e0 = fexp2(v0 * 1.4426950408889634f);
                float e1 = fexp2(v1 * 1.4426950408889634f);
                vh_s[l] = pack_f16(xt2.x * e0, xt2.y * e1);  // UNNORMALIZED
                if (bt == 0) st_flag(&xw_flag, (uint32)(t + 1));
                __builtin_amdgcn_s_setprio(2);
                // off-chain: sum-reduce + inv; ph5 consumers gated via cnt4 (13th add)
                float ssum = e0 + e1;
#pragma unroll
                for (int off = 32; off > 0; off >>= 1) ssum += __shfl_xor(ssum, off);
                if (bt == 0) { inv_s = frcp(ssum); add_flag(&cnt4, 1); }
            }
            // ph5: gate reduce + LSTM pointwise (all 4 B-waves; thread = h-unit j)
            spin_busy(&cnt4, (uint32)(13 * (t + 1)));
            const float inv = inv_s;
            const int j = bt;
            // h partials (slots 0-3) plain; xw partials (slots 4-5) scaled by inv
            float gi = bi0 + part4[j] + part4[1024 + j] + part4[2048 + j] + part4[3072 + j]
                     + (part4[4096 + j] + part4[5120 + j]) * inv;
            float gf = bf0 + part4[256 + j] + part4[1280 + j] + part4[2304 + j] + part4[3328 + j]
                     + (part4[4352 + j] + part4[5376 + j]) * inv;
            float gg = bg0 + part4[512 + j] + part4[1536 + j] + part4[2560 + j] + part4[3584 + j]
                     + (part4[4608 + j] + part4[5632 + j]) * inv;
            float go = bo0 + part4[768 + j] + part4[1792 + j] + part4[2816 + j] + part4[3840 + j]
                     + (part4[4864 + j] + part4[5888 + j]) * inv;
            float c = c_s[j];
            float c2 = fast_sigmoid(gf) * c + fast_sigmoid(gi) * fast_tanh(gg);
            float h2v = fast_sigmoid(go) * fast_tanh(c2);
            c_s[j] = c2;
            float hn = __shfl_xor(h2v, 1);
            float cn = __shfl_xor(c2, 1);
            if (!(j & 1)) {
                uint32 hp = pack_f16(h2v, hn);
                vh_s[64 + (j >> 1)] = hp;       // v h-pairs for gate GEMV
                hsh_s[j >> 1] = hp;             // hs h-pairs for ph1
                hsh_s[128 + (j >> 1)] = pack_f16(c2, cn);  // hs c-pairs
            }
            if (l == 0) add_flag(&cnt5, 1);     // A-waves spin on cnt5 directly
            // global store AFTER the release: keep its vmcnt off the handoff path
            out[(t * 128 + b) * 256 + j] = h2v;
        }
    }
#undef NP_BLOCK
}

extern "C" void kernel_launch(void* const* d_in, const int* in_sizes, int n_in,
                              void* d_out, int out_size, void* d_ws, size_t ws_size,
                              hipStream_t stream) {
    const float* x    = (const float*)d_in[0];
    const float* We   = (const float*)d_in[1];
    const float* Ue   = (const float*)d_in[2];
    const float* v_e  = (const float*)d_in[3];
    const float* W_ih = (const float*)d_in[4];
    const float* W_hh = (const float*)d_in[5];
    const float* b_ih = (const float*)d_in[6];
    const float* b_hh = (const float*)d_in[7];
    float* out = (float*)d_out;

    char* w = (char*)d_ws;
    unsigned short* Uxg = (unsigned short*)w;      // 4 MB
    uint32* We2 = (uint32*)(w + 4194304);          // 128 KB
    uint32* Wc2 = (uint32*)(w + 4325376);          // 768 KB

    prep_weights<<<896, 256, 0, stream>>>(We, W_ih, W_hh, We2, Wc2);
    ux_kernel<<<256, 512, 0, stream>>>(x, Ue, Uxg);
    encoder_kernel<<<128, NT, 0, stream>>>(x, v_e, b_ih, b_hh, Uxg,
                                           (const uint4*)We2, (const uint4*)Wc2, out);
}